// Round 3
// baseline (37.005 us; speedup 1.0000x reference)
//
#include <hip/hip_runtime.h>

#define NPTS 1024
#define RES 0.2592f
#define CMIN (319.5f * 0.2592f)   // (640/2 - 0.5) * 0.2592

// DIAGNOSTIC ROUND: Round-1 kernel (unchanged math/output) + an extra
// 28 KiB/wave coalesced dummy read stream from d_ws (total +117 MB) to
// measure marginal HBM read bandwidth and surface our dispatch in rocprof
// top-5. Real outputs are identical to Round 1.
__global__ __launch_bounds__(256, 4) void kabsch_kernel(
    const float* __restrict__ kp,   // (2*B, NPTS, 2)
    const float* __restrict__ tg,   // (B, NPTS, 2)
    const float* __restrict__ wt,   // (B, NPTS)
    const int4* __restrict__ ws,    // dummy stream (poisoned scratch)
    long ws_mod,                    // usable int4 span minus 1792 (0 = skip)
    float* __restrict__ outR,       // (B, 9)
    float* __restrict__ outT)       // (B, 3)
{
    const int wave = threadIdx.x >> 6;
    const int lane = threadIdx.x & 63;
    const int b    = blockIdx.x * 4 + wave;

    const float2* wp = (const float2*)(wt + (long)b * NPTS);
    const float4* sp = (const float4*)(kp + (long)(2 * b) * NPTS * 2);
    const float4* tp = (const float4*)(tg + (long)b * NPTS * 2);

    float acc[9];
#pragma unroll
    for (int i = 0; i < 9; ++i) acc[i] = 0.f;

#pragma unroll
    for (int c = 0; c < 8; ++c) {
        const int idx = lane + 64 * c;
        float4 s4 = sp[idx];
        float4 t4 = tp[idx];
        float2 w2 = wp[idx];

#pragma unroll
        for (int k = 0; k < 2; ++k) {
            float px = k ? s4.z : s4.x;
            float py = k ? s4.w : s4.y;
            float qx = k ? t4.z : t4.x;
            float qy = k ? t4.w : t4.y;
            float w  = k ? w2.y : w2.x;

            float sx = CMIN - RES * py;
            float sy = RES * px - CMIN;
            float tx = CMIN - RES * qy;
            float ty = RES * qx - CMIN;
            float wtx = w * tx;
            float wty = w * ty;
            acc[0] += w;
            acc[1] += w * sx;
            acc[2] += w * sy;
            acc[3] += wtx;
            acc[4] += wty;
            acc[5] += wtx * sx;
            acc[6] += wtx * sy;
            acc[7] += wty * sx;
            acc[8] += wty * sy;
        }
    }

    // ---- dummy diagnostic stream: 28 x int4 per lane = 28 KiB per wave ----
    if (ws_mod > 0) {
        const long gwave = (long)blockIdx.x * 4 + wave;
        const long base  = (gwave * 1792L) % ws_mod;  // 1792 int4 = 28 KiB/wave
        int ax = 0, ay = 0, az = 0, aw = 0;
#pragma unroll
        for (int c = 0; c < 28; ++c) {
            int4 v = ws[base + (long)c * 64 + lane];
            ax ^= v.x; ay ^= v.y; az ^= v.z; aw ^= v.w;
        }
        // keep loads alive; condition is (effectively) never true, but the
        // compiler cannot prove it, so no DCE and no per-load serialization.
        if (ax == (int)0xDEADBEEF && ay == (int)0x13371337 &&
            az == (int)0x5A5A5A5A && aw == (int)0xC0FFEE00) {
            ((int*)ws)[0] = ax;
        }
    }

    // single 64-lane butterfly reduce per batch
#pragma unroll
    for (int i = 0; i < 9; ++i) {
#pragma unroll
        for (int off = 32; off >= 1; off >>= 1)
            acc[i] += __shfl_xor(acc[i], off, 64);
    }

    if (lane == 0) {
        const float Sw  = acc[0];
        const float Ssx = acc[1], Ssy = acc[2];
        const float Stx = acc[3], Sty = acc[4];
        const float M00 = acc[5], M01 = acc[6], M10 = acc[7], M11 = acc[8];

        const float a  = M00 * Sw - Stx * Ssx;
        const float bb = M01 * Sw - Stx * Ssy;
        const float c  = M10 * Sw - Sty * Ssx;
        const float d  = M11 * Sw - Sty * Ssy;
        const float det = a * d - bb * c;

        float Q00, Q01, Q10, Q11, sgn;
        if (det >= 0.f) {
            float p = a + d, q = c - bb;
            float h = rsqrtf(p * p + q * q);
            p *= h; q *= h;
            Q00 = p;  Q01 = -q;
            Q10 = q;  Q11 = p;
            sgn = 1.f;
        } else {
            float p = a - d, q = bb + c;
            float h = rsqrtf(p * p + q * q);
            p *= h; q *= h;
            Q00 = p;  Q01 = q;
            Q10 = q;  Q11 = -p;
            sgn = -1.f;
        }

        const float inv = 1.f / Sw;
        const float sbx = Ssx * inv, sby = Ssy * inv;
        const float tbx = Stx * inv, tby = Sty * inv;

        const float t1x = sbx - (Q00 * tbx + Q10 * tby);
        const float t1y = sby - (Q01 * tbx + Q11 * tby);
        const float t2x = -(Q00 * t1x + Q01 * t1y);
        const float t2y = -(Q10 * t1x + Q11 * t1y);

        float* r = outR + (long)b * 9;
        r[0] = Q00; r[1] = Q10; r[2] = 0.f;
        r[3] = Q01; r[4] = Q11; r[5] = 0.f;
        r[6] = 0.f; r[7] = 0.f; r[8] = sgn;

        float* t = outT + (long)b * 3;
        t[0] = t2x; t[1] = t2y; t[2] = 0.f;
    }
}

extern "C" void kernel_launch(void* const* d_in, const int* in_sizes, int n_in,
                              void* d_out, int out_size, void* d_ws, size_t ws_size,
                              hipStream_t stream) {
    const float* kp = (const float*)d_in[0];  // (8192, 1024, 2)
    const float* tg = (const float*)d_in[1];  // (4096, 1024, 2)
    const float* wt = (const float*)d_in[2];  // (4096, 1024)

    const int B = in_sizes[2] / NPTS;         // 4096
    float* outR = (float*)d_out;              // B*9
    float* outT = (float*)d_out + (long)B * 9;

    long ws_mod = (long)(ws_size / 16) - 1792L - 64L;
    if (ws_mod < 1) ws_mod = 0;

    kabsch_kernel<<<B / 4, 256, 0, stream>>>(kp, tg, wt,
                                             (const int4*)d_ws, ws_mod,
                                             outR, outT);
}

// Round 4
// 20.385 us; speedup vs baseline: 1.8153x; 1.8153x over previous
//
#include <hip/hip_runtime.h>

#define NPTS 1024
#define RES 0.2592f
#define CMIN (319.5f * 0.2592f)   // (640/2 - 0.5) * 0.2592

// One WAVE per batch element. 256 threads = 4 waves = 4 batches per block.
// Grid = B/4 = 1024 blocks.
// Roofline note (R3 diagnostic): mandatory traffic = 83.9 MB read once at the
// measured ~7.07 TB/s achievable ceiling (11.9 us) + ~8.5 us fixed dispatch
// overhead = 20.4 us observed. Structure-invariant (R0 vs R1 identical).
__global__ __launch_bounds__(256, 4) void kabsch_kernel(
    const float* __restrict__ kp,   // (2*B, NPTS, 2) pixel coords; batch b uses row 2b
    const float* __restrict__ tg,   // (B, NPTS, 2)
    const float* __restrict__ wt,   // (B, NPTS)
    float* __restrict__ outR,       // (B, 9)  = R_tgt_src^T row-major
    float* __restrict__ outT)       // (B, 3)  = t_src_tgt_intgt
{
    const int wave = threadIdx.x >> 6;
    const int lane = threadIdx.x & 63;
    const int b    = blockIdx.x * 4 + wave;

    const float2* wp = (const float2*)(wt + (long)b * NPTS);
    const float4* sp = (const float4*)(kp + (long)(2 * b) * NPTS * 2);
    const float4* tp = (const float4*)(tg + (long)b * NPTS * 2);

    float acc[9];
#pragma unroll
    for (int i = 0; i < 9; ++i) acc[i] = 0.f;

    // 8 coalesced chunks: float4 covers 2 points; float2 covers their 2 weights.
#pragma unroll
    for (int c = 0; c < 8; ++c) {
        const int idx = lane + 64 * c;
        float4 s4 = sp[idx];
        float4 t4 = tp[idx];
        float2 w2 = wp[idx];

#pragma unroll
        for (int k = 0; k < 2; ++k) {
            float px = k ? s4.z : s4.x;
            float py = k ? s4.w : s4.y;
            float qx = k ? t4.z : t4.x;
            float qy = k ? t4.w : t4.y;
            float w  = k ? w2.y : w2.x;

            // radar-frame transform
            float sx = CMIN - RES * py;
            float sy = RES * px - CMIN;
            float tx = CMIN - RES * qy;
            float ty = RES * qx - CMIN;
            float wtx = w * tx;
            float wty = w * ty;
            acc[0] += w;
            acc[1] += w * sx;
            acc[2] += w * sy;
            acc[3] += wtx;
            acc[4] += wty;
            acc[5] += wtx * sx;
            acc[6] += wtx * sy;
            acc[7] += wty * sx;
            acc[8] += wty * sy;
        }
    }

    // single 64-lane butterfly reduce per batch
#pragma unroll
    for (int i = 0; i < 9; ++i) {
#pragma unroll
        for (int off = 32; off >= 1; off >>= 1)
            acc[i] += __shfl_xor(acc[i], off, 64);
    }

    if (lane == 0) {
        const float Sw  = acc[0];
        const float Ssx = acc[1], Ssy = acc[2];
        const float Stx = acc[3], Sty = acc[4];
        const float M00 = acc[5], M01 = acc[6], M10 = acc[7], M11 = acc[8];

        // W2 * Sw^2 (positive scale irrelevant for the polar factor)
        const float a  = M00 * Sw - Stx * Ssx;
        const float bb = M01 * Sw - Stx * Ssy;
        const float c  = M10 * Sw - Sty * Ssx;
        const float d  = M11 * Sw - Sty * Ssy;
        const float det = a * d - bb * c;

        float Q00, Q01, Q10, Q11, sgn;
        if (det >= 0.f) {
            float p = a + d, q = c - bb;
            float h = rsqrtf(p * p + q * q);
            p *= h; q *= h;
            Q00 = p;  Q01 = -q;
            Q10 = q;  Q11 = p;
            sgn = 1.f;
        } else {
            float p = a - d, q = bb + c;
            float h = rsqrtf(p * p + q * q);
            p *= h; q *= h;
            Q00 = p;  Q01 = q;
            Q10 = q;  Q11 = -p;
            sgn = -1.f;
        }

        const float inv = 1.f / Sw;
        const float sbx = Ssx * inv, sby = Ssy * inv;
        const float tbx = Stx * inv, tby = Sty * inv;

        // t1 = src_centroid - R^T * tgt_centroid
        const float t1x = sbx - (Q00 * tbx + Q10 * tby);
        const float t1y = sby - (Q01 * tbx + Q11 * tby);
        // t2 = -R * t1
        const float t2x = -(Q00 * t1x + Q01 * t1y);
        const float t2y = -(Q10 * t1x + Q11 * t1y);

        // output 0: R^T row-major = [[Q00,Q10,0],[Q01,Q11,0],[0,0,sgn]]
        float* r = outR + (long)b * 9;
        r[0] = Q00; r[1] = Q10; r[2] = 0.f;
        r[3] = Q01; r[4] = Q11; r[5] = 0.f;
        r[6] = 0.f; r[7] = 0.f; r[8] = sgn;

        float* t = outT + (long)b * 3;
        t[0] = t2x; t[1] = t2y; t[2] = 0.f;
    }
}

extern "C" void kernel_launch(void* const* d_in, const int* in_sizes, int n_in,
                              void* d_out, int out_size, void* d_ws, size_t ws_size,
                              hipStream_t stream) {
    const float* kp = (const float*)d_in[0];  // (8192, 1024, 2)
    const float* tg = (const float*)d_in[1];  // (4096, 1024, 2)
    const float* wt = (const float*)d_in[2];  // (4096, 1024)

    const int B = in_sizes[2] / NPTS;         // 4096
    float* outR = (float*)d_out;              // B*9
    float* outT = (float*)d_out + (long)B * 9;

    kabsch_kernel<<<B / 4, 256, 0, stream>>>(kp, tg, wt, outR, outT);
}